// Round 6
// baseline (427.227 us; speedup 1.0000x reference)
//
#include <hip/hip_runtime.h>

typedef __attribute__((ext_vector_type(4))) float f4;
typedef __attribute__((ext_vector_type(8))) short s8;

__device__ __forceinline__ unsigned short f2bf(float x){
  unsigned u = __float_as_uint(x);
  u += 0x7fffu + ((u >> 16) & 1u);
  return (unsigned short)(u >> 16);
}
__device__ __forceinline__ float lrelu(float v){ return v > 0.f ? v : 0.2f * v; }
__device__ __forceinline__ void gload16(const unsigned short* g, unsigned short* l){
  __builtin_amdgcn_global_load_lds((const __attribute__((address_space(1))) unsigned int*)g,
                                   (__attribute__((address_space(3))) unsigned int*)l, 16, 0, 0);
}

// ================= K1: merged prep =================
// blocks [0,512): W2/W0 -> bf16 transpose;  [512,768): zero + pq = W @ a;  [768,780): HE = exer @ W
__global__ __launch_bounds__(256) void prep(const float* __restrict__ Wg,
    const float* __restrict__ a_src, const float* __restrict__ a_dst,
    const float* __restrict__ exer, float* __restrict__ pq, float* __restrict__ zbase,
    unsigned short* __restrict__ W2T, unsigned short* __restrict__ W0T,
    float* __restrict__ HE2, float* __restrict__ HE0)
{
  __shared__ float tile[32][33];
  __shared__ float xs[512];
  const int b = blockIdx.x, t = threadIdx.x;
  if (b < 512){
    const int m = b >> 8, kb = (b & 15) * 32, nb = ((b >> 4) & 15) * 32;
    const float* W = Wg + (m == 0 ? 2 * 262144 : 0);
    unsigned short* WT = (m == 0) ? W2T : W0T;
    const int tx = t & 31, ty = t >> 5;
    #pragma unroll
    for (int i = 0; i < 32; i += 8) tile[ty + i][tx] = W[(kb + ty + i) * 512 + nb + tx];
    __syncthreads();
    #pragma unroll
    for (int i = 0; i < 32; i += 8) WT[(nb + ty + i) * 512 + kb + tx] = f2bf(tile[tx][ty + i]);
  } else if (b < 768){
    const int tid = (b - 512) * 256 + t;
    if (tid < 55424) zbase[tid] = 0.f;        // CrawP3,CrawP1,denP3,denP1,Bb,Cc
    const int wid = tid >> 6, lane = tid & 63;
    for (int task = wid; task < 4096; task += 1024){
      int g = task >> 10, isq = (task >> 9) & 1, r = task & 511;
      const float* w = Wg + ((g * 512 + r) << 9);
      const float* a = (isq ? a_dst : a_src) + g * 512;
      float s = 0.f;
      for (int i = lane; i < 512; i += 64) s += w[i] * a[i];
      for (int off = 32; off; off >>= 1) s += __shfl_down(s, off);
      if (lane == 0) pq[task] = s;
    }
  } else {
    const int b3 = b - 768;                    // 0..11
    const int g = (b3 < 6) ? 0 : 2, e = b3 % 6;
    xs[t] = exer[e * 512 + t]; xs[t + 256] = exer[e * 512 + 256 + t];
    __syncthreads();
    const float* W = Wg + g * 262144;
    float a0 = 0.f, a1 = 0.f;
    #pragma unroll 8
    for (int k = 0; k < 512; k++){ float xv = xs[k]; a0 += xv * W[k * 512 + t]; a1 += xv * W[k * 512 + 256 + t]; }
    float* HE = (g == 0) ? HE0 : HE2;
    HE[e * 512 + t] = a0; HE[e * 512 + 256 + t] = a1;
  }
}

// ================= K2: pass1 (per-row scalars + send accumulation), 2-deep pipeline =================
template<int DEG>
__device__ void pass1_body(float* sC, float* sDen, float* sASE, float* sADE,
                           int bid, int nblk, const float* __restrict__ x,
                           const float* __restrict__ exer, const float* __restrict__ pq,
                           int gA, int gB, const int* __restrict__ idx,
                           float* __restrict__ alph, float* __restrict__ CrawP,
                           float* __restrict__ denP, int M)
{
  const int t = threadIdx.x, lane = t & 63, w = t >> 6;
  for (int i = t; i < 3072; i += 256) sC[i] = 0.f;
  if (t < 6) sDen[t] = 0.f;
  // inline 12 scalar dots: sASE[e] = exer_e . pq[gA].src ; sADE[e] = exer_e . pq[gB].dst
  for (int d = w * 3; d < w * 3 + 3; d++){
    const float* X = exer + (d % 6) * 512;
    const float* V = (d < 6) ? (pq + gA * 1024) : (pq + gB * 1024 + 512);
    float s = 0.f;
    for (int i = lane; i < 512; i += 64) s += X[i] * V[i];
    for (int off = 32; off; off >>= 1) s += __shfl_down(s, off);
    if (lane == 0) ((d < 6) ? sASE : sADE)[d % 6] = s;
  }
  __syncthreads();

  const int kb = lane * 8;
  const float* pqA = pq + gA * 1024;
  const float* pqB = pq + gB * 1024;
  f4 pA0 = *(const f4*)(pqA + kb),       pA1 = *(const f4*)(pqA + kb + 4);
  f4 qA0 = *(const f4*)(pqA + 512 + kb), qA1 = *(const f4*)(pqA + 512 + kb + 4);
  f4 pB0 = *(const f4*)(pqB + kb),       pB1 = *(const f4*)(pqB + kb + 4);
  const float aseR = sASE[lane % 6];
  const float adeR = sADE[lane % 6];

  float cacc[6][8];
  #pragma unroll
  for (int e = 0; e < 6; e++)
    #pragma unroll
    for (int i = 0; i < 8; i++) cacc[e][i] = 0.f;
  float dacc[6] = {0.f,0.f,0.f,0.f,0.f,0.f};

  const int nw = nblk * 4;
  int r = bid * 4 + w;
  if (r < M){
    const float* xr = x + (size_t)r * 512 + kb;
    f4 x0 = *(const f4*)(xr), x1 = *(const f4*)(xr + 4);
    int ei[DEG];
    #pragma unroll
    for (int j = 0; j < DEG; j++) ei[j] = idx[r * DEG + j];
    while (true){
      // prefetch next row while computing current
      const int rn = r + nw;
      f4 y0, y1; int ein[DEG];
      if (rn < M){
        const float* xn = x + (size_t)rn * 512 + kb;
        y0 = *(const f4*)(xn); y1 = *(const f4*)(xn + 4);
        #pragma unroll
        for (int j = 0; j < DEG; j++) ein[j] = idx[rn * DEG + j];
      }
      // ---- compute current row ----
      float dP = 0.f, dQ = 0.f, dB = 0.f;
      #pragma unroll
      for (int i = 0; i < 4; i++){
        dP += x0[i]*pA0[i] + x1[i]*pA1[i];
        dQ += x0[i]*qA0[i] + x1[i]*qA1[i];
        dB += x0[i]*pB0[i] + x1[i]*pB1[i];
      }
      #pragma unroll
      for (int off = 1; off < 64; off <<= 1){
        dP += __shfl_xor(dP, off); dQ += __shfl_xor(dQ, off); dB += __shfl_xor(dB, off);
      }
      float scS = lrelu(dP + dQ);
      float sc[DEG], m = scS;
      #pragma unroll
      for (int j = 0; j < DEG; j++){ sc[j] = lrelu(__shfl(aseR, ei[j]) + dQ); m = fmaxf(m, sc[j]); }
      float eS = __expf(scS - m), sum = eS;
      float ev[DEG];
      #pragma unroll
      for (int j = 0; j < DEG; j++){ ev[j] = __expf(sc[j] - m); sum += ev[j]; }
      float inv = 1.f / sum;
      float val = 0.f;
      if (lane == 0) val = eS * inv;
      else if (lane < 7){
        #pragma unroll
        for (int j = 0; j < DEG; j++) val += (ei[j] == lane - 1) ? ev[j] * inv : 0.f;
      }
      if (lane < 8) alph[(size_t)r * 8 + lane] = val;
      float wj[DEG];
      #pragma unroll
      for (int j = 0; j < DEG; j++) wj[j] = __expf(lrelu(dB + __shfl(adeR, ei[j])));
      #pragma unroll
      for (int e = 0; e < 6; e++){
        float we = 0.f;
        #pragma unroll
        for (int j = 0; j < DEG; j++) we += (ei[j] == e) ? wj[j] : 0.f;
        dacc[e] += we;
        #pragma unroll
        for (int i = 0; i < 4; i++){ cacc[e][i] += we * x0[i]; cacc[e][4+i] += we * x1[i]; }
      }
      // ---- advance ----
      if (rn >= M) break;
      r = rn; x0 = y0; x1 = y1;
      #pragma unroll
      for (int j = 0; j < DEG; j++) ei[j] = ein[j];
    }
  }
  // block-level reduction then one sliced global atomic pass
  #pragma unroll
  for (int e = 0; e < 6; e++)
    #pragma unroll
    for (int i = 0; i < 8; i++)
      atomicAdd(&sC[e * 512 + kb + i], cacc[e][i]);
  if (lane == 0){
    #pragma unroll
    for (int e = 0; e < 6; e++) atomicAdd(&sDen[e], dacc[e]);
  }
  __syncthreads();
  float* Cslice = CrawP + (bid & 7) * 3072;
  for (int i = t; i < 3072; i += 256){
    float v = sC[i];
    if (v != 0.f) atomicAdd(&Cslice[i], v);
  }
  if (t < 6) atomicAdd(&denP[(bid & 7) * 8 + t], sDen[t]);
}

__global__ __launch_bounds__(256) void pass1_all(const float* __restrict__ stu,
    const float* __restrict__ kn, const float* __restrict__ exer,
    const float* __restrict__ pq, const int* __restrict__ e_ue, const int* __restrict__ e_ke,
    float* __restrict__ alphS, float* __restrict__ alphK,
    float* __restrict__ CrawP3, float* __restrict__ CrawP1,
    float* __restrict__ denP3, float* __restrict__ denP1)
{
  __shared__ float sC[3072];
  __shared__ float sDen[6], sASE[6], sADE[6];
  if (blockIdx.x < 1528)
    pass1_body<3>(sC, sDen, sASE, sADE, blockIdx.x, 1528, stu, exer, pq, 2, 3,
                  e_ue, alphS, CrawP3, denP3, 50000);
  else
    pass1_body<4>(sC, sDen, sASE, sADE, blockIdx.x - 1528, 8, kn, exer, pq, 0, 1,
                  e_ke, alphK, CrawP1, denP1, 512);
}

// ================= K3: m97-style GEMM (BM=128,BN=128,BK=32, 2-phase) + fused epilogue =================
__launch_bounds__(256, 3)
__global__ void gemm_all(const float* __restrict__ stu, const float* __restrict__ kn,
                         const unsigned short* __restrict__ W2T, const unsigned short* __restrict__ W0T,
                         const float* __restrict__ alphS, const float* __restrict__ alphK,
                         const float* __restrict__ HE2, const float* __restrict__ HE0,
                         const float* __restrict__ b_gat, float* __restrict__ outS,
                         float* __restrict__ outK)
{
  __shared__ __align__(16) unsigned short sA[8192];   // 2 bufs x [128 rows][4 slots of 8], slot^=(row>>1)&3
  __shared__ __align__(16) unsigned short sB[8192];
  __shared__ __align__(16) float sAl[1024];
  __shared__ __align__(16) float sHEb[768];
  __shared__ __align__(16) float sBias[128];

  // bijective XCD chunking, nb-fastest within each mb
  const int nwg = gridDim.x;
  const int q = nwg >> 3, rr = nwg & 7;
  const int xcd = blockIdx.x & 7, pos = blockIdx.x >> 3;
  const int wido = (xcd < rr ? xcd * (q + 1) : rr * (q + 1) + (xcd - rr) * q) + pos;

  const float* x; const unsigned short* WT; const float* alph; const float* HE;
  const float* bias; float* outp; int M, mb, nb;
  if (wido < 1564){
    x = stu; WT = W2T; alph = alphS; HE = HE2; bias = b_gat + 1024; outp = outS; M = 50000;
    mb = wido >> 2; nb = wido & 3;
  } else {
    const int w2 = wido - 1564;
    x = kn; WT = W0T; alph = alphK; HE = HE0; bias = b_gat; outp = outK; M = 512;
    mb = w2 >> 2; nb = w2 & 3;
  }
  const int r0 = mb * 128, n0 = nb * 128;
  const int tid = threadIdx.x, lane = tid & 63, w = tid >> 6;
  const int wr = w >> 1, wc = w & 1, l16 = lane & 15, lhi = lane >> 4;

  // A staging: thread -> row=tid>>1, half=(tid&1)
  const int arow = tid >> 1, akh = (tid & 1) * 16;
  const float* aptr = x + (size_t)min(r0 + arow, M - 1) * 512 + akh;
  const int akey = (arow >> 1) & 3, s0 = (tid & 1) * 2;
  const int dA0 = arow * 32 + ((s0 ^ akey) << 3);
  const int dA1 = arow * 32 + (((s0 + 1) ^ akey) << 3);

  // B staging: thread -> row=tid>>2 (+64), slot=tid&3; source pre-swizzled
  const int brow = tid >> 2, bslot = tid & 3;
  const int bkey = (brow >> 1) & 3;
  const unsigned short* gB0 = WT + (size_t)(n0 + brow) * 512 + ((bslot ^ bkey) << 3);
  const unsigned short* gB1 = gB0 + (size_t)64 * 512;
  unsigned short* lB0 = sB + tid * 8;
  unsigned short* lB1 = sB + 2048 + tid * 8;

  // reader offsets (invariant across kt)
  int aoff[4], boff[4];
  #pragma unroll
  for (int m = 0; m < 4; m++){
    const int ra = wr * 64 + m * 16 + l16;
    aoff[m] = ra * 32 + ((lhi ^ ((ra >> 1) & 3)) << 3);
    const int rb = wc * 64 + m * 16 + l16;
    boff[m] = rb * 32 + ((lhi ^ ((rb >> 1) & 3)) << 3);
  }

  // ---- prologue: stage kt=0 + aux ----
  gload16(gB0, lB0); gload16(gB1, lB1);
  f4 c0 = *(const f4*)(aptr),     c1 = *(const f4*)(aptr + 4);
  f4 c2 = *(const f4*)(aptr + 8), c3 = *(const f4*)(aptr + 12);
  {
    s8 p0, p1;
    #pragma unroll
    for (int i = 0; i < 4; i++){
      p0[i] = (short)f2bf(c0[i]); p0[4+i] = (short)f2bf(c1[i]);
      p1[i] = (short)f2bf(c2[i]); p1[4+i] = (short)f2bf(c3[i]);
    }
    *(s8*)(sA + dA0) = p0; *(s8*)(sA + dA1) = p1;
  }
  { const int rw = min(r0 + (tid >> 1), M - 1);
    *(f4*)(sAl + tid * 4) = *(const f4*)(alph + (size_t)rw * 8 + (tid & 1) * 4); }
  if (tid < 192) *(f4*)(sHEb + tid * 4) = *(const f4*)(HE + (tid >> 5) * 512 + n0 + (tid & 31) * 4);
  else if (tid < 224){ const int i2 = tid - 192; *(f4*)(sBias + i2 * 4) = *(const f4*)(bias + n0 + i2 * 4); }
  __syncthreads();

  f4 acc[4][4];
  #pragma unroll
  for (int m = 0; m < 4; m++)
    #pragma unroll
    for (int n = 0; n < 4; n++) acc[m][n] = (f4){0.f, 0.f, 0.f, 0.f};

  int bufo = 0;
  #pragma unroll 1
  for (int kt = 0; kt < 16; kt++){
    const int nxt = bufo ^ 4096;
    if (kt < 15){
      gload16(gB0 + (kt + 1) * 32, lB0 + nxt);
      gload16(gB1 + (kt + 1) * 32, lB1 + nxt);
      c0 = *(const f4*)(aptr + (kt + 1) * 32);     c1 = *(const f4*)(aptr + (kt + 1) * 32 + 4);
      c2 = *(const f4*)(aptr + (kt + 1) * 32 + 8); c3 = *(const f4*)(aptr + (kt + 1) * 32 + 12);
    }
    s8 af[4], bf[4];
    #pragma unroll
    for (int m = 0; m < 4; m++) af[m] = *(const s8*)(sA + bufo + aoff[m]);
    #pragma unroll
    for (int n = 0; n < 4; n++) bf[n] = *(const s8*)(sB + bufo + boff[n]);
    #pragma unroll
    for (int m = 0; m < 4; m++)
      #pragma unroll
      for (int n = 0; n < 4; n++)
        acc[m][n] = __builtin_amdgcn_mfma_f32_16x16x32_bf16(af[m], bf[n], acc[m][n], 0, 0, 0);
    if (kt < 15){
      s8 p0, p1;
      #pragma unroll
      for (int i = 0; i < 4; i++){
        p0[i] = (short)f2bf(c0[i]); p0[4+i] = (short)f2bf(c1[i]);
        p1[i] = (short)f2bf(c2[i]); p1[4+i] = (short)f2bf(c3[i]);
      }
      *(s8*)(sA + nxt + dA0) = p0; *(s8*)(sA + nxt + dA1) = p1;
    }
    __syncthreads();
    bufo = nxt;
  }

  // ---- epilogue: out = x + a_self*(x@W) + sum_e coef_e*HE[e] + b ----
  float hec[4][6], bi[4];
  #pragma unroll
  for (int n = 0; n < 4; n++){
    const int cl = wc * 64 + n * 16 + l16;
    bi[n] = sBias[cl];
    #pragma unroll
    for (int e = 0; e < 6; e++) hec[n][e] = sHEb[e * 128 + cl];
  }
  #pragma unroll
  for (int m = 0; m < 4; m++){
    #pragma unroll
    for (int j = 0; j < 4; j++){
      const int rl = wr * 64 + m * 16 + lhi * 4 + j;
      const int gr = r0 + rl;
      if (gr < M){
        f4 alA = *(const f4*)(sAl + rl * 8);
        f4 alB = *(const f4*)(sAl + rl * 8 + 4);
        #pragma unroll
        for (int n = 0; n < 4; n++){
          const int gc = n0 + wc * 64 + n * 16 + l16;
          float v = x[(size_t)gr * 512 + gc] + alA[0] * acc[m][n][j] + bi[n];
          v += alA[1] * hec[n][0] + alA[2] * hec[n][1] + alA[3] * hec[n][2];
          v += alB[0] * hec[n][3] + alB[1] * hec[n][4] + alB[2] * hec[n][5];
          outp[(size_t)gr * 512 + gc] = v;
        }
      }
    }
  }
}

// ================= K4: finalize B (GAT1) / C (GAT3), split-k, 8-slice reduce =================
__global__ __launch_bounds__(512) void fin_bc(const float* __restrict__ exer,
    const float* __restrict__ Wg, const float* __restrict__ pq,
    const float* __restrict__ CrawP3, const float* __restrict__ denP3,
    const float* __restrict__ CrawP1, const float* __restrict__ denP1,
    const float* __restrict__ b_gat, float* __restrict__ B, float* __restrict__ C)
{
  const int b = blockIdx.x, ks = blockIdx.y;
  const int isC = (b >= 6) ? 1 : 0, e = b % 6, g = isC ? 3 : 1;
  const float* CrawP = isC ? CrawP3 : CrawP1;
  const float* denP  = isC ? denP3  : denP1;
  __shared__ float mix[64];
  __shared__ float sdots[2];
  const int t = threadIdx.x, lane = t & 63, w = t >> 6;
  if (w < 2){
    const float* V = pq + g * 1024 + w * 512;
    const float* X = exer + e * 512;
    float s = 0.f;
    for (int i = lane; i < 512; i += 64) s += X[i] * V[i];
    for (int off = 32; off; off >>= 1) s += __shfl_down(s, off);
    if (lane == 0) sdots[w] = s;
  }
  __syncthreads();
  const float wself = __expf(lrelu(sdots[0] + sdots[1]));
  float dn = wself;
  #pragma unroll
  for (int s = 0; s < 8; s++) dn += denP[s * 8 + e];
  if (t < 64){
    const int k = ks * 64 + t;
    float cr = 0.f;
    #pragma unroll
    for (int s = 0; s < 8; s++) cr += CrawP[s * 3072 + e * 512 + k];
    mix[t] = (cr + wself * exer[e * 512 + k]) / dn;
  }
  __syncthreads();
  const float* W = Wg + g * 262144 + ks * 64 * 512;
  float acc = 0.f;
  #pragma unroll 4
  for (int kk = 0; kk < 64; kk++) acc += mix[kk] * W[kk * 512 + t];
  if (ks == 0) acc += b_gat[g * 512 + t];
  atomicAdd(&(isC ? C : B)[e * 512 + t], acc);
}

// ================= K5: final exercise attention =================
__global__ __launch_bounds__(512) void fin_exer(const float* __restrict__ exer,
    const float* __restrict__ B, const float* __restrict__ C,
    const float* __restrict__ attn_w, const float* __restrict__ attn_b,
    float* __restrict__ outE)
{
  __shared__ float s1[6], s2[6];
  const int t = threadIdx.x, wid = t >> 6, lane = t & 63;
  for (int task = wid; task < 12; task += 8){
    int e = task >> 1, which = task & 1;
    const float* w = attn_w + (which + 1) * 1024;
    const float* X = exer + e * 512;
    const float* Y = (which ? C : B) + e * 512;
    float s = 0.f;
    for (int i = lane; i < 512; i += 64) s += X[i] * w[i] + Y[i] * w[512 + i];
    for (int off = 32; off; off >>= 1) s += __shfl_down(s, off);
    if (lane == 0) (which ? s2 : s1)[e] = s + attn_b[which + 1];
  }
  __syncthreads();
  for (int i = t; i < 3072; i += 512){
    int e = i >> 9;
    float a = s1[e], b = s2[e];
    float m = fmaxf(a, b);
    float ea = __expf(a - m), eb = __expf(b - m);
    float inv = 1.f / (ea + eb);
    outE[i] = exer[i] + (ea * inv) * B[i] + (eb * inv) * C[i];
  }
}

extern "C" void kernel_launch(void* const* d_in, const int* in_sizes, int n_in,
                              void* d_out, int out_size, void* d_ws, size_t ws_size,
                              hipStream_t stream){
  const float* kn     = (const float*)d_in[0];
  const float* exer   = (const float*)d_in[1];
  const float* stu    = (const float*)d_in[2];
  const float* Wg     = (const float*)d_in[3];
  const float* a_src  = (const float*)d_in[4];
  const float* a_dst  = (const float*)d_in[5];
  const float* b_gat  = (const float*)d_in[6];
  const float* attn_w = (const float*)d_in[7];
  const float* attn_b = (const float*)d_in[8];
  const int*   e_ke   = (const int*)d_in[9];
  const int*   e_ue   = (const int*)d_in[11];
  float* out = (float*)d_out;

  unsigned short* W2T = (unsigned short*)d_ws;
  unsigned short* W0T = W2T + 262144;
  float* pq     = (float*)(W0T + 262144);   // 4096
  float* CrawP3 = pq + 4096;                // 8*3072  -- zero region start (55424 floats)
  float* CrawP1 = CrawP3 + 24576;           // 8*3072
  float* denP3  = CrawP1 + 24576;           // 64
  float* denP1  = denP3 + 64;               // 64
  float* Bb     = denP1 + 64;               // 3072
  float* Cc     = Bb + 3072;                // 3072  -- zero region end
  float* HE2    = Cc + 3072;                // 3072
  float* HE0    = HE2 + 3072;               // 3072
  float* alphS  = HE0 + 3072;               // 400384
  float* alphK  = alphS + 400384;           // 4096

  hipLaunchKernelGGL(prep, dim3(780), dim3(256), 0, stream,
                     Wg, a_src, a_dst, exer, pq, CrawP3, W2T, W0T, HE2, HE0);
  hipLaunchKernelGGL(pass1_all, dim3(1536), dim3(256), 0, stream,
                     stu, kn, exer, pq, e_ue, e_ke, alphS, alphK, CrawP3, CrawP1, denP3, denP1);
  hipLaunchKernelGGL(gemm_all, dim3(1580), dim3(256), 0, stream,
                     stu, kn, W2T, W0T, alphS, alphK, HE2, HE0, b_gat, out + 265216, out);
  hipLaunchKernelGGL(fin_bc, dim3(12, 8), dim3(512), 0, stream,
                     exer, Wg, pq, CrawP3, denP3, CrawP1, denP1, b_gat, Bb, Cc);
  hipLaunchKernelGGL(fin_exer, dim3(1), dim3(512), 0, stream,
                     exer, Bb, Cc, attn_w, attn_b, out + 262144);
}